// Round 12
// baseline (118.841 us; speedup 1.0000x reference)
//
#include <hip/hip_runtime.h>
#include <hip/hip_bf16.h>

#define N_ROWS 8192
#define DIM 256
#define NANCH 64
#define NVIEW 128
#define NPART 8     // column partitions (8 anchors = 1024 cols each)

typedef __attribute__((ext_vector_type(8))) short bf16x8;
typedef __attribute__((ext_vector_type(16))) float f32x16;
typedef __attribute__((ext_vector_type(4))) float float4v;
typedef __attribute__((ext_vector_type(4))) unsigned short ushort4v;

__device__ __forceinline__ unsigned short f2bf(float x) {
  union { float f; unsigned int u; } c; c.f = x;
  unsigned int u = c.u;
  unsigned int r = (u + 0x7fffu + ((u >> 16) & 1u)) >> 16;
  return (unsigned short)r;
}

__device__ __forceinline__ float bf2f(unsigned short b) {
  union { unsigned int u; float f; } c; c.u = ((unsigned int)b) << 16;
  return c.f;
}

__device__ __forceinline__ void gload_lds16(const void* g, void* l) {
  __builtin_amdgcn_global_load_lds(
      (const __attribute__((address_space(1))) unsigned int*)g,
      (__attribute__((address_space(3))) unsigned int*)l, 16, 0, 0);
}

// fp32 -> bf16 with 1/sqrt(T) prescale, fused with per-row squared-norm
// (= the Gram diagonal = the row max of the logits). One wave per row.
__global__ void cast_diag_kernel(const float4v* __restrict__ in,
                                 ushort4v* __restrict__ out,
                                 float* __restrict__ diag) {
  const int w = threadIdx.x >> 6;
  const int l = threadIdx.x & 63;
  const int row = blockIdx.x * 4 + w;
  const float s = 3.16227766016838f; // 1/sqrt(0.1)
  float4v v = in[row * 64 + l];
  ushort4v o;
  o.x = f2bf(v.x * s);
  o.y = f2bf(v.y * s);
  o.z = f2bf(v.z * s);
  o.w = f2bf(v.w * s);
  out[row * 64 + l] = o;
  float c0 = bf2f(o.x), c1 = bf2f(o.y), c2 = bf2f(o.z), c3 = bf2f(o.w);
  float ss = c0 * c0 + c1 * c1 + c2 * c2 + c3 * c3;
#pragma unroll
  for (int st = 1; st < 64; st <<= 1) ss += __shfl_xor(ss, st);
  if (l == 0) diag[row] = ss;
}

// -------- Kernel 2: fused pass over (256 rows x 1024 cols) per block.
// grid = 32 row-blocks x 8 parts = 256 blocks (1/CU -- co-residency never
// materializes, so ALL overlap is in-block). 512 threads = 8 waves
// (4 row-groups x 2 col-groups); wave owns 64 rows x 32 cols per tile.
// Streams 16 B tiles (64 cols x K=256 = 32 KB, k-major conflict-free)
// through a ring-2. m201-style FINE phases: each tile = 2 phases (K-half);
// per phase: {stage half of next tile (2 gload_lds) -> counted vmcnt(4)
// [confirms the half staged 2 phases ago; NEVER 0 mid-loop] -> s_barrier ->
// 8 ds_read_b128 + 16 MFMA (4 chains by ks-parity) -> s_barrier}.
// Barrier cadence ~1k cy (R8 was ~6.7k with one big cluster -> 29% util).
// Ring-2 WAR safety: end barrier of tile t-1 phase 1 precedes any stage of
// tile t+1 (same slot). Row max is KNOWN (= diag). Verified fused epilogue:
//   NEG anchors -> ns += exp(v - diag)   [underflow-skipped]
//   POS anchors -> sd += (v - diag); ep += exp(v - diag) [diag masked]
__global__ __launch_bounds__(512, 2) void pcl_negsum(
    const unsigned short* __restrict__ Xb, const int* __restrict__ labels,
    const float* __restrict__ diag, float* __restrict__ ns_partial,
    float* __restrict__ sd_partial, float* __restrict__ ep_partial) {
  const int bx = blockIdx.x;
  const int part = bx & 7;            // same part -> same XCD (L2 panel reuse)
  const int rb = bx >> 3;             // rows rb*256 .. +255
  const int abase = part * 8;         // 8 col-anchors = 1024 cols
  const int tid = threadIdx.x;        // 0..511
  const int wid = tid >> 6;           // 0..7
  const int lane = tid & 63;
  const int l31 = lane & 31;
  const int khalf = lane >> 5;
  const int rg = wid >> 1;            // row group (64 rows)
  const int cg = wid & 1;             // col group (32 cols)
  const int R0 = rb * 256;

  __shared__ __align__(16) unsigned short ring[2 * 64 * DIM];  // 2 x 32 KB
  __shared__ float sdiag[256];
  __shared__ float nsacc[256];
  __shared__ float sdacc[256];
  __shared__ float epacc[256];
  __shared__ int slab[NANCH];

  if (tid < NANCH) slab[tid] = labels[tid];
  if (tid < 256) {
    sdiag[tid] = diag[R0 + tid];
    nsacc[tid] = 0.f;
    sdacc[tid] = 0.f;
    epacc[tid] = 0.f;
  }
  __syncthreads();
  const int myAnch = rb * 2 + (rg >> 1);  // wave's 64 rows lie in this anchor
  const int myLab = slab[myAnch];

  // A fragments: lane holds row R0 + rg*64 + ri*32 + l31, k = ks*16+khalf*8.
  bf16x8 afrag[2][16];
#pragma unroll
  for (int ri = 0; ri < 2; ++ri) {
#pragma unroll
    for (int ks = 0; ks < 16; ++ks) {
      const unsigned short* p =
          Xb + (size_t)(R0 + rg * 64 + ri * 32 + l31) * DIM + ks * 16 + khalf * 8;
      afrag[ri][ks] = *(const bf16x8*)p;
    }
  }
#pragma unroll
  for (int ri = 0; ri < 2; ++ri)
#pragma unroll
    for (int ks = 0; ks < 16; ++ks) asm volatile("" : "+v"(afrag[ri][ks]));
  // Drain A loads so the counted-vmcnt bookkeeping below is exact.
  asm volatile("s_waitcnt vmcnt(0)");

  // Wave-uniform skip threshold: min diag over this wave's 64 rows - 40.
  float thr;
  {
    float d = sdiag[rg * 64 + lane];
#pragma unroll
    for (int st = 1; st < 64; st <<= 1) d = fminf(d, __shfl_xor(d, st));
    thr = d - 40.f;
  }

  char* const L0 = (char*)&ring[0];

  // Tile layout in LDS slot: [k-octet 0..31][col 0..63][16B] (32 KB).
  // Stage group (T,P) = k-octets P*16..+15 (16 KB): wave w instr i covers
  // octet P*16 + w*2+i, cols 0..63 (lane). Per-lane global src; LDS dest
  // wave-uniform base + lane*16 (HW).
#define STAGE(T, P)                                                             \
  do {                                                                          \
    const unsigned short* _s =                                                  \
        Xb + (size_t)(part * 1024 + (T) * 64 + lane) * DIM +                    \
        ((P) * 16 + wid * 2) * 8;                                               \
    char* _d = L0 + ((T) & 1) * 32768 + (P) * 16384 + wid * 2048;               \
    gload_lds16(_s, _d);                                                        \
    gload_lds16(_s + 8, _d + 1024);                                             \
  } while (0)

#define MFMA32(A, B, C) __builtin_amdgcn_mfma_f32_32x32x16_bf16(A, B, C, 0, 0, 0)

  // Phase (T,P): vmcnt(4) confirms group (T,P) (own 2 instrs), issued 2
  // phases ago; 4 = the 2 newer groups still allowed in flight.
#define PHASE(T, P, VN)                                                         \
  do {                                                                          \
    if ((T) < 15) STAGE((T) + 1, (P));                                          \
    asm volatile("s_waitcnt vmcnt(" VN ")");                                    \
    __builtin_amdgcn_sched_barrier(0);                                          \
    __builtin_amdgcn_s_barrier();                                               \
    __builtin_amdgcn_sched_barrier(0);                                          \
    {                                                                           \
      const char* _sb = L0 + ((T) & 1) * 32768 + (P) * 16384 +                  \
                        khalf * 1024 + (cg * 32 + l31) * 16;                    \
      __builtin_amdgcn_s_setprio(1);                                            \
      _Pragma("unroll") for (int ks = 0; ks < 8; ks += 2) {                     \
        bf16x8 b0 = *(const bf16x8*)(_sb + (ks * 2) * 1024);                    \
        bf16x8 b1 = *(const bf16x8*)(_sb + (ks * 2 + 2) * 1024);                \
        a0A = MFMA32(afrag[0][(P) * 8 + ks], b0, a0A);                          \
        a1A = MFMA32(afrag[1][(P) * 8 + ks], b0, a1A);                          \
        a0B = MFMA32(afrag[0][(P) * 8 + ks + 1], b1, a0B);                      \
        a1B = MFMA32(afrag[1][(P) * 8 + ks + 1], b1, a1B);                      \
      }                                                                         \
      __builtin_amdgcn_s_setprio(0);                                            \
    }                                                                           \
    __builtin_amdgcn_sched_barrier(0);                                          \
    __builtin_amdgcn_s_barrier();                                               \
  } while (0)

  // Epilogue for tile T (outside phase fences; registers + LDS atomics only).
#define EPI(T)                                                                  \
  do {                                                                          \
    const int aT = abase + ((T) >> 1);                                          \
    const bool is_pos = (slab[aT] == myLab);                                    \
    f32x16 c0 = a0A + a0B;                                                      \
    f32x16 c1 = a1A + a1B;                                                      \
    float vmax = fmaxf(c0[0], c1[0]);                                           \
    _Pragma("unroll") for (int r = 1; r < 16; ++r)                              \
        vmax = fmaxf(vmax, fmaxf(c0[r], c1[r]));                                \
    const bool anyhot = __any(vmax > thr);                                      \
    const int gcol = part * 1024 + (T) * 64 + cg * 32 + l31;                    \
    if (__builtin_expect(is_pos, 0)) {                                          \
      if (!anyhot) {                                                            \
        _Pragma("unroll") for (int ri = 0; ri < 2; ++ri) {                      \
          _Pragma("unroll") for (int r = 0; r < 16; ++r) {                      \
            const int rloc = (r & 3) + 8 * (r >> 2) + 4 * khalf;                \
            const int row = rg * 64 + ri * 32 + rloc;                           \
            float d = (ri ? c1[r] : c0[r]) - sdiag[row];                        \
            _Pragma("unroll") for (int st = 1; st < 32; st <<= 1)               \
                d += __shfl_xor(d, st);                                         \
            if (l31 == 0) atomicAdd(&sdacc[row], d);                            \
          }                                                                     \
        }                                                                       \
      } else {                                                                  \
        _Pragma("unroll") for (int ri = 0; ri < 2; ++ri) {                      \
          _Pragma("unroll") for (int r = 0; r < 16; ++r) {                      \
            const int rloc = (r & 3) + 8 * (r >> 2) + 4 * khalf;                \
            const int row = rg * 64 + ri * 32 + rloc;                           \
            const bool isdiag = (R0 + row) == gcol;                             \
            float v = (ri ? c1[r] : c0[r]);                                     \
            float d = v - sdiag[row];                                           \
            float sd_e = isdiag ? 0.f : d;                                      \
            float e = (!isdiag && d > -40.f) ? __expf(d) : 0.f;                 \
            _Pragma("unroll") for (int st = 1; st < 32; st <<= 1) {             \
              sd_e += __shfl_xor(sd_e, st);                                     \
              e += __shfl_xor(e, st);                                           \
            }                                                                   \
            if (l31 == 0) {                                                     \
              atomicAdd(&sdacc[row], sd_e);                                     \
              if (e != 0.f) atomicAdd(&epacc[row], e);                          \
            }                                                                   \
          }                                                                     \
        }                                                                       \
      }                                                                         \
    } else if (__builtin_expect(anyhot, 0)) {                                   \
      _Pragma("unroll") for (int ri = 0; ri < 2; ++ri) {                        \
        _Pragma("unroll") for (int r = 0; r < 16; ++r) {                        \
          const int rloc = (r & 3) + 8 * (r >> 2) + 4 * khalf;                  \
          const int row = rg * 64 + ri * 32 + rloc;                             \
          float d = (ri ? c1[r] : c0[r]) - sdiag[row];                          \
          float e = (d > -40.f) ? __expf(d) : 0.f;                              \
          _Pragma("unroll") for (int st = 1; st < 32; st <<= 1)                 \
              e += __shfl_xor(e, st);                                           \
          if (l31 == 0) atomicAdd(&nsacc[row], e);                              \
        }                                                                       \
      }                                                                         \
    }                                                                           \
  } while (0)

  // prologue: stage both halves of tile 0
  STAGE(0, 0);
  STAGE(0, 1);

  for (int t = 0; t < 15; ++t) {
    f32x16 a0A = {}, a0B = {}, a1A = {}, a1B = {};
    PHASE(t, 0, "4");
    PHASE(t, 1, "4");
    EPI(t);
  }
  {
    f32x16 a0A = {}, a0B = {}, a1A = {}, a1B = {};
    PHASE(15, 0, "2");
    PHASE(15, 1, "0");
    EPI(15);
  }

#undef EPI
#undef PHASE
#undef MFMA32
#undef STAGE

  __syncthreads();
  if (tid < 256) {
    ns_partial[part * N_ROWS + R0 + tid] = nsacc[tid];
    sd_partial[part * N_ROWS + R0 + tid] = sdacc[tid];
    ep_partial[part * N_ROWS + R0 + tid] = epacc[tid];
  }
}

// -------- Kernel 3: per-row combine. 32 blocks x 256 threads, 1 row/thread.
// mean_log_prob_pos = (SD - npos*log(NS+eps) - EP/(NS+eps)) / npos
__global__ void pcl_combine(const int* __restrict__ labels,
                            const float* __restrict__ ns_partial,
                            const float* __restrict__ sd_partial,
                            const float* __restrict__ ep_partial,
                            float* __restrict__ partials) {
  const int tid = threadIdx.x;
  const int row = blockIdx.x * 256 + tid;
  __shared__ int slab[NANCH];
  __shared__ float sred[256];
  if (tid < NANCH) slab[tid] = labels[tid];
  __syncthreads();

  const int lab = slab[row >> 7];
  int cnt = 0;
#pragma unroll
  for (int b = 0; b < NANCH; ++b) cnt += (slab[b] == lab) ? 1 : 0;

  float NS = 0.f, SD = 0.f, EP = 0.f;
#pragma unroll
  for (int p = 0; p < NPART; ++p) {
    NS += ns_partial[p * N_ROWS + row];
    SD += sd_partial[p * N_ROWS + row];
    EP += ep_partial[p * N_ROWS + row];
  }
  const float npos = (float)(cnt * NVIEW - 1);
  const float nse = NS + 1e-10f;
  const float mlpp = (SD - npos * __logf(nse) - EP / nse) / npos;
  sred[tid] = mlpp;
  __syncthreads();
  for (int st = 128; st > 0; st >>= 1) {
    if (tid < st) sred[tid] += sred[tid + st];
    __syncthreads();
  }
  if (tid == 0) partials[blockIdx.x] = sred[0];
}

__global__ void final_reduce(const float* __restrict__ partials, float* __restrict__ out) {
  __shared__ float s[32];
  int t = threadIdx.x;
  if (t < 32) s[t] = partials[t];
  __syncthreads();
  if (t == 0) {
    float sum = 0.f;
    for (int r = 0; r < 32; ++r) sum += s[r];
    out[0] = -(0.1f / 0.07f) * sum / (float)N_ROWS;
  }
}

extern "C" void kernel_launch(void* const* d_in, const int* in_sizes, int n_in,
                              void* d_out, int out_size, void* d_ws, size_t ws_size,
                              hipStream_t stream) {
  const float* feats = (const float*)d_in[0];
  const int* labels = (const int*)d_in[1];
  float* out = (float*)d_out;

  char* base = (char*)d_ws;
  unsigned short* Xb = (unsigned short*)d_ws;                      // 4 MB
  size_t off = (size_t)N_ROWS * DIM * 2;
  float* diag = (float*)(base + off);       off += N_ROWS * 4;     // 32 KB
  float* ns_partial = (float*)(base + off); off += (size_t)NPART * N_ROWS * 4;
  float* sd_partial = (float*)(base + off); off += (size_t)NPART * N_ROWS * 4;
  float* ep_partial = (float*)(base + off); off += (size_t)NPART * N_ROWS * 4;
  float* partials = (float*)(base + off);

  cast_diag_kernel<<<N_ROWS / 4, 256, 0, stream>>>((const float4v*)feats,
                                                   (ushort4v*)Xb, diag);
  pcl_negsum<<<32 * NPART, 512, 0, stream>>>(Xb, labels, diag, ns_partial,
                                             sd_partial, ep_partial);
  pcl_combine<<<N_ROWS / 256, 256, 0, stream>>>(labels, ns_partial, sd_partial,
                                                ep_partial, partials);
  final_reduce<<<1, 64, 0, stream>>>(partials, out);
}

// Round 13
// 102.451 us; speedup vs baseline: 1.1600x; 1.1600x over previous
//
#include <hip/hip_runtime.h>
#include <hip/hip_bf16.h>

#define N_ROWS 8192
#define DIM 256
#define NANCH 64
#define NVIEW 128
#define NPART 8     // column partitions (8 anchors = 1024 cols each)

typedef __attribute__((ext_vector_type(8))) short bf16x8;
typedef __attribute__((ext_vector_type(16))) float f32x16;
typedef __attribute__((ext_vector_type(4))) float float4v;
typedef __attribute__((ext_vector_type(4))) unsigned short ushort4v;

__device__ __forceinline__ unsigned short f2bf(float x) {
  union { float f; unsigned int u; } c; c.f = x;
  unsigned int u = c.u;
  unsigned int r = (u + 0x7fffu + ((u >> 16) & 1u)) >> 16;
  return (unsigned short)r;
}

__device__ __forceinline__ float bf2f(unsigned short b) {
  union { unsigned int u; float f; } c; c.u = ((unsigned int)b) << 16;
  return c.f;
}

// fp32 -> bf16 with 1/sqrt(T) prescale, fused with per-row squared-norm
// (= the Gram diagonal = the row max of the logits). One wave per row.
__global__ void cast_diag_kernel(const float4v* __restrict__ in,
                                 ushort4v* __restrict__ out,
                                 float* __restrict__ diag) {
  const int w = threadIdx.x >> 6;
  const int l = threadIdx.x & 63;
  const int row = blockIdx.x * 4 + w;
  const float s = 3.16227766016838f; // 1/sqrt(0.1)
  float4v v = in[row * 64 + l];
  ushort4v o;
  o.x = f2bf(v.x * s);
  o.y = f2bf(v.y * s);
  o.z = f2bf(v.z * s);
  o.w = f2bf(v.w * s);
  out[row * 64 + l] = o;
  float c0 = bf2f(o.x), c1 = bf2f(o.y), c2 = bf2f(o.z), c3 = bf2f(o.w);
  float ss = c0 * c0 + c1 * c1 + c2 * c2 + c3 * c3;
#pragma unroll
  for (int st = 1; st < 64; st <<= 1) ss += __shfl_xor(ss, st);
  if (l == 0) diag[row] = ss;
}

// -------- Kernel 2: fused pass over (256 rows x 1024 cols) per block.
// grid = 32 row-blocks x 8 parts = 256 blocks (1/CU). part = bx&7 -> all
// blocks reading panel p land on XCD p: the 512 KB B panel is L2-RESIDENT.
// So: NO LDS staging, NO barriers. 8 waves (4 row-groups x 2 col-groups)
// drift freely; each wave owns 64 rows x 32 cols and reads its B fragments
// DIRECTLY from L2 via global_load_dwordx4, quarter-pipelined (load next
// 4-fragment group, then 8 MFMAs on the previous group) so ~200cy L2 latency
// hides under 256 SIMD-cy of MFMA. 4 independent MFMA chains of depth 8.
// launch_bounds(512,2) -> 256 VGPRs: afrag(128)+acc(64)+B(48) finally FITS
// (rounds 4-12 all reported VGPR<=124 => A-fragments were never resident).
// LDS holds only the 4 KB accumulators. Row max is KNOWN (= diag).
//   NEG anchors -> ns += exp(v - diag)   [underflow-skipped]
//   POS anchors -> sd += (v - diag); ep += exp(v - diag) [diag masked]
__global__ __launch_bounds__(512, 2) void pcl_negsum(
    const unsigned short* __restrict__ Xb, const int* __restrict__ labels,
    const float* __restrict__ diag, float* __restrict__ ns_partial,
    float* __restrict__ sd_partial, float* __restrict__ ep_partial) {
  const int bx = blockIdx.x;
  const int part = bx & 7;            // same part -> same XCD (L2 panel reuse)
  const int rb = bx >> 3;             // rows rb*256 .. +255
  const int abase = part * 8;         // 8 col-anchors = 1024 cols
  const int tid = threadIdx.x;        // 0..511
  const int wid = tid >> 6;           // 0..7
  const int lane = tid & 63;
  const int l31 = lane & 31;
  const int khalf = lane >> 5;
  const int rg = wid >> 1;            // row group (64 rows)
  const int cg = wid & 1;             // col group (32 cols)
  const int R0 = rb * 256;

  __shared__ float sdiag[256];
  __shared__ float nsacc[256];
  __shared__ float sdacc[256];
  __shared__ float epacc[256];
  __shared__ int slab[NANCH];

  if (tid < NANCH) slab[tid] = labels[tid];
  if (tid < 256) {
    sdiag[tid] = diag[R0 + tid];
    nsacc[tid] = 0.f;
    sdacc[tid] = 0.f;
    epacc[tid] = 0.f;
  }
  __syncthreads();
  const int myAnch = rb * 2 + (rg >> 1);  // wave's 64 rows lie in this anchor
  const int myLab = slab[myAnch];

  // A fragments: lane holds row R0 + rg*64 + ri*32 + l31, k = ks*16+khalf*8.
  bf16x8 afrag[2][16];
#pragma unroll
  for (int ri = 0; ri < 2; ++ri) {
#pragma unroll
    for (int ks = 0; ks < 16; ++ks) {
      const unsigned short* p =
          Xb + (size_t)(R0 + rg * 64 + ri * 32 + l31) * DIM + ks * 16 + khalf * 8;
      afrag[ri][ks] = *(const bf16x8*)p;
    }
  }
#pragma unroll
  for (int ri = 0; ri < 2; ++ri)
#pragma unroll
    for (int ks = 0; ks < 16; ++ks) asm volatile("" : "+v"(afrag[ri][ks]));

  // Wave-uniform skip threshold: min diag over this wave's 64 rows - 40.
  float thr;
  {
    float d = sdiag[rg * 64 + lane];
#pragma unroll
    for (int st = 1; st < 64; st <<= 1) d = fminf(d, __shfl_xor(d, st));
    thr = d - 40.f;
  }

#define MFMA32(A, B, C) __builtin_amdgcn_mfma_f32_32x32x16_bf16(A, B, C, 0, 0, 0)

  // B fragment pointer: col = part*1024 + t*64 + cg*32 + l31 (per lane),
  // k-offset ks*16 + khalf*8. Same fragment layout as afrag (verified).
  const unsigned short* bp =
      Xb + (size_t)(part * 1024 + cg * 32 + l31) * DIM + khalf * 8;

  bf16x8 q0[4], q1[4], q2[4], q3[4];
#pragma unroll
  for (int k = 0; k < 4; ++k) q0[k] = *(const bf16x8*)(bp + k * 16);

  for (int t = 0; t < 16; ++t) {
    const unsigned short* bt = bp + (size_t)t * 64 * DIM;
    const unsigned short* bn = bt + (size_t)64 * DIM;
    f32x16 c00 = {}, c01 = {}, c10 = {}, c11 = {};

#pragma unroll
    for (int k = 0; k < 4; ++k) q1[k] = *(const bf16x8*)(bt + (4 + k) * 16);
#pragma unroll
    for (int k = 0; k < 4; ++k) {
      c00 = MFMA32(afrag[0][k], q0[k], c00);
      c10 = MFMA32(afrag[1][k], q0[k], c10);
    }
#pragma unroll
    for (int k = 0; k < 4; ++k) q2[k] = *(const bf16x8*)(bt + (8 + k) * 16);
#pragma unroll
    for (int k = 0; k < 4; ++k) {
      c00 = MFMA32(afrag[0][4 + k], q1[k], c00);
      c10 = MFMA32(afrag[1][4 + k], q1[k], c10);
    }
#pragma unroll
    for (int k = 0; k < 4; ++k) q3[k] = *(const bf16x8*)(bt + (12 + k) * 16);
#pragma unroll
    for (int k = 0; k < 4; ++k) {
      c01 = MFMA32(afrag[0][8 + k], q2[k], c01);
      c11 = MFMA32(afrag[1][8 + k], q2[k], c11);
    }
    if (t < 15) {
#pragma unroll
      for (int k = 0; k < 4; ++k) q0[k] = *(const bf16x8*)(bn + k * 16);
    }
#pragma unroll
    for (int k = 0; k < 4; ++k) {
      c01 = MFMA32(afrag[0][12 + k], q3[k], c01);
      c11 = MFMA32(afrag[1][12 + k], q3[k], c11);
    }

    // ---- fused epilogue for tile t (registers + LDS atomics; no barrier) --
    {
      const int aT = abase + (t >> 1);
      const bool is_pos = (slab[aT] == myLab);
      f32x16 c0 = c00 + c01;
      f32x16 c1 = c10 + c11;
      float vmax = fmaxf(c0[0], c1[0]);
#pragma unroll
      for (int r = 1; r < 16; ++r) vmax = fmaxf(vmax, fmaxf(c0[r], c1[r]));
      const bool anyhot = __any(vmax > thr);
      const int gcol = part * 1024 + t * 64 + cg * 32 + l31;
      if (__builtin_expect(is_pos, 0)) {
        if (!anyhot) {
#pragma unroll
          for (int ri = 0; ri < 2; ++ri) {
#pragma unroll
            for (int r = 0; r < 16; ++r) {
              const int rloc = (r & 3) + 8 * (r >> 2) + 4 * khalf;
              const int row = rg * 64 + ri * 32 + rloc;
              float d = (ri ? c1[r] : c0[r]) - sdiag[row];
#pragma unroll
              for (int st = 1; st < 32; st <<= 1) d += __shfl_xor(d, st);
              if (l31 == 0) atomicAdd(&sdacc[row], d);
            }
          }
        } else {
#pragma unroll
          for (int ri = 0; ri < 2; ++ri) {
#pragma unroll
            for (int r = 0; r < 16; ++r) {
              const int rloc = (r & 3) + 8 * (r >> 2) + 4 * khalf;
              const int row = rg * 64 + ri * 32 + rloc;
              const bool isdiag = (R0 + row) == gcol;
              float v = (ri ? c1[r] : c0[r]);
              float d = v - sdiag[row];
              float sd_e = isdiag ? 0.f : d;
              float e = (!isdiag && d > -40.f) ? __expf(d) : 0.f;
#pragma unroll
              for (int st = 1; st < 32; st <<= 1) {
                sd_e += __shfl_xor(sd_e, st);
                e += __shfl_xor(e, st);
              }
              if (l31 == 0) {
                atomicAdd(&sdacc[row], sd_e);
                if (e != 0.f) atomicAdd(&epacc[row], e);
              }
            }
          }
        }
      } else if (__builtin_expect(anyhot, 0)) {
#pragma unroll
        for (int ri = 0; ri < 2; ++ri) {
#pragma unroll
          for (int r = 0; r < 16; ++r) {
            const int rloc = (r & 3) + 8 * (r >> 2) + 4 * khalf;
            const int row = rg * 64 + ri * 32 + rloc;
            float d = (ri ? c1[r] : c0[r]) - sdiag[row];
            float e = (d > -40.f) ? __expf(d) : 0.f;
#pragma unroll
            for (int st = 1; st < 32; st <<= 1) e += __shfl_xor(e, st);
            if (l31 == 0) atomicAdd(&nsacc[row], e);
          }
        }
      }
    }
  }

#undef MFMA32

  __syncthreads();
  if (tid < 256) {
    ns_partial[part * N_ROWS + R0 + tid] = nsacc[tid];
    sd_partial[part * N_ROWS + R0 + tid] = sdacc[tid];
    ep_partial[part * N_ROWS + R0 + tid] = epacc[tid];
  }
}

// -------- Kernel 3: per-row combine. 32 blocks x 256 threads, 1 row/thread.
// mean_log_prob_pos = (SD - npos*log(NS+eps) - EP/(NS+eps)) / npos
__global__ void pcl_combine(const int* __restrict__ labels,
                            const float* __restrict__ ns_partial,
                            const float* __restrict__ sd_partial,
                            const float* __restrict__ ep_partial,
                            float* __restrict__ partials) {
  const int tid = threadIdx.x;
  const int row = blockIdx.x * 256 + tid;
  __shared__ int slab[NANCH];
  __shared__ float sred[256];
  if (tid < NANCH) slab[tid] = labels[tid];
  __syncthreads();

  const int lab = slab[row >> 7];
  int cnt = 0;
#pragma unroll
  for (int b = 0; b < NANCH; ++b) cnt += (slab[b] == lab) ? 1 : 0;

  float NS = 0.f, SD = 0.f, EP = 0.f;
#pragma unroll
  for (int p = 0; p < NPART; ++p) {
    NS += ns_partial[p * N_ROWS + row];
    SD += sd_partial[p * N_ROWS + row];
    EP += ep_partial[p * N_ROWS + row];
  }
  const float npos = (float)(cnt * NVIEW - 1);
  const float nse = NS + 1e-10f;
  const float mlpp = (SD - npos * __logf(nse) - EP / nse) / npos;
  sred[tid] = mlpp;
  __syncthreads();
  for (int st = 128; st > 0; st >>= 1) {
    if (tid < st) sred[tid] += sred[tid + st];
    __syncthreads();
  }
  if (tid == 0) partials[blockIdx.x] = sred[0];
}

__global__ void final_reduce(const float* __restrict__ partials, float* __restrict__ out) {
  __shared__ float s[32];
  int t = threadIdx.x;
  if (t < 32) s[t] = partials[t];
  __syncthreads();
  if (t == 0) {
    float sum = 0.f;
    for (int r = 0; r < 32; ++r) sum += s[r];
    out[0] = -(0.1f / 0.07f) * sum / (float)N_ROWS;
  }
}

extern "C" void kernel_launch(void* const* d_in, const int* in_sizes, int n_in,
                              void* d_out, int out_size, void* d_ws, size_t ws_size,
                              hipStream_t stream) {
  const float* feats = (const float*)d_in[0];
  const int* labels = (const int*)d_in[1];
  float* out = (float*)d_out;

  char* base = (char*)d_ws;
  unsigned short* Xb = (unsigned short*)d_ws;                      // 4 MB
  size_t off = (size_t)N_ROWS * DIM * 2;
  float* diag = (float*)(base + off);       off += N_ROWS * 4;     // 32 KB
  float* ns_partial = (float*)(base + off); off += (size_t)NPART * N_ROWS * 4;
  float* sd_partial = (float*)(base + off); off += (size_t)NPART * N_ROWS * 4;
  float* ep_partial = (float*)(base + off); off += (size_t)NPART * N_ROWS * 4;
  float* partials = (float*)(base + off);

  cast_diag_kernel<<<N_ROWS / 4, 256, 0, stream>>>((const float4v*)feats,
                                                   (ushort4v*)Xb, diag);
  pcl_negsum<<<32 * NPART, 512, 0, stream>>>(Xb, labels, diag, ns_partial,
                                             sd_partial, ep_partial);
  pcl_combine<<<N_ROWS / 256, 256, 0, stream>>>(labels, ns_partial, sd_partial,
                                                ep_partial, partials);
  final_reduce<<<1, 64, 0, stream>>>(partials, out);
}

// Round 14
// 82.291 us; speedup vs baseline: 1.4441x; 1.2450x over previous
//
#include <hip/hip_runtime.h>
#include <hip/hip_bf16.h>

#define N_ROWS 8192
#define DIM 256
#define NANCH 64
#define NVIEW 128
#define NPART 8     // column partitions (8 anchors = 1024 cols each)

typedef __attribute__((ext_vector_type(8))) short bf16x8;
typedef __attribute__((ext_vector_type(16))) float f32x16;
typedef __attribute__((ext_vector_type(4))) float float4v;
typedef __attribute__((ext_vector_type(4))) unsigned short ushort4v;

__device__ __forceinline__ unsigned short f2bf(float x) {
  union { float f; unsigned int u; } c; c.f = x;
  unsigned int u = c.u;
  unsigned int r = (u + 0x7fffu + ((u >> 16) & 1u)) >> 16;
  return (unsigned short)r;
}

__device__ __forceinline__ float bf2f(unsigned short b) {
  union { unsigned int u; float f; } c; c.u = ((unsigned int)b) << 16;
  return c.f;
}

// fp32 -> bf16 (1/sqrt(T) prescale) into FRAGMENT-LINEAR layout + row norms.
// Layout: for colblk = row>>5, ks = k>>4: a 1 KB block at (colblk*16+ks)*1024
// holding cell (khalf*32 + row&31)*16B = 8 bf16 (k = ks*16+khalf*8..+8).
// A wave's MFMA fragment load (lane -> cell lane) is then ONE coalesced 1 KB
// global_load_dwordx4 -- rounds 1-13 used row-major, where every fragment
// load had 512B lane stride = 64 cache lines per instruction (the systemic
// bottleneck). One wave per row; lane l covers elements l*4..l*4+3.
__global__ void cast_diag_kernel(const float4v* __restrict__ in,
                                 char* __restrict__ Xf,
                                 float* __restrict__ diag) {
  const int w = threadIdx.x >> 6;
  const int l = threadIdx.x & 63;
  const int row = blockIdx.x * 4 + w;
  const float s = 3.16227766016838f; // 1/sqrt(0.1)
  float4v v = in[row * 64 + l];
  ushort4v o;
  o.x = f2bf(v.x * s);
  o.y = f2bf(v.y * s);
  o.z = f2bf(v.z * s);
  o.w = f2bf(v.w * s);
  const size_t off = ((size_t)((row >> 5) * 16 + (l >> 2))) * 1024 +
                     ((l >> 1) & 1) * 512 + (row & 31) * 16 + (l & 1) * 8;
  *(ushort4v*)(Xf + off) = o;
  float c0 = bf2f(o.x), c1 = bf2f(o.y), c2 = bf2f(o.z), c3 = bf2f(o.w);
  float ss = c0 * c0 + c1 * c1 + c2 * c2 + c3 * c3;
#pragma unroll
  for (int st = 1; st < 64; st <<= 1) ss += __shfl_xor(ss, st);
  if (l == 0) diag[row] = ss;
}

// -------- Kernel 2: fused pass over (256 rows x 1024 cols) per block.
// grid = 32 row-blocks x 8 parts = 256 blocks (1/CU); part = bx&7 pins each
// 512 KB B panel to one XCD's L2. NO LDS staging, NO barriers: 8 waves
// (4 row-groups x 2 col-groups) drift freely; wave = 64 rows x 32 cols.
// ALL fragment loads (A and B) are single coalesced 1 KB loads from the
// fragment-linear Xf. B uses a static q0/q1 ping-pong (4 fragments = 4 KB
// contiguous per group; depth-1 prefetch; 2 waves/SIMD co-hide latency).
// 4 independent MFMA chains of depth 8. Row max is KNOWN (= diag).
//   NEG anchors -> ns += exp(v - diag)   [underflow-skipped]
//   POS anchors -> sd += (v - diag); ep += exp(v - diag) [diag masked]
__global__ __launch_bounds__(512, 2) void pcl_negsum(
    const char* __restrict__ Xf, const int* __restrict__ labels,
    const float* __restrict__ diag, float* __restrict__ ns_partial,
    float* __restrict__ sd_partial, float* __restrict__ ep_partial) {
  const int bx = blockIdx.x;
  const int part = bx & 7;            // same part -> same XCD (L2 panel reuse)
  const int rb = bx >> 3;             // rows rb*256 .. +255
  const int abase = part * 8;         // 8 col-anchors = 1024 cols
  const int tid = threadIdx.x;        // 0..511
  const int wid = tid >> 6;           // 0..7
  const int lane = tid & 63;
  const int l31 = lane & 31;
  const int khalf = lane >> 5;
  const int rg = wid >> 1;            // row group (64 rows)
  const int cg = wid & 1;             // col group (32 cols)
  const int R0 = rb * 256;

  __shared__ float sdiag[256];
  __shared__ float nsacc[256];
  __shared__ float sdacc[256];
  __shared__ float epacc[256];
  __shared__ int slab[NANCH];

  if (tid < NANCH) slab[tid] = labels[tid];
  if (tid < 256) {
    sdiag[tid] = diag[R0 + tid];
    nsacc[tid] = 0.f;
    sdacc[tid] = 0.f;
    epacc[tid] = 0.f;
  }
  __syncthreads();
  const int myAnch = rb * 2 + (rg >> 1);  // wave's 64 rows lie in this anchor
  const int myLab = slab[myAnch];

  // A fragments: colblk = rb*8 + rg*2 + ri; one coalesced 1 KB load each.
  bf16x8 afrag[2][16];
#pragma unroll
  for (int ri = 0; ri < 2; ++ri) {
#pragma unroll
    for (int ks = 0; ks < 16; ++ks) {
      const char* p = Xf +
          ((size_t)((rb * 8 + rg * 2 + ri) * 16 + ks)) * 1024 + lane * 16;
      afrag[ri][ks] = *(const bf16x8*)p;
    }
  }
#pragma unroll
  for (int ri = 0; ri < 2; ++ri)
#pragma unroll
    for (int ks = 0; ks < 16; ++ks) asm volatile("" : "+v"(afrag[ri][ks]));

  // Wave-uniform skip threshold: min diag over this wave's 64 rows - 40.
  float thr;
  {
    float d = sdiag[rg * 64 + lane];
#pragma unroll
    for (int st = 1; st < 64; st <<= 1) d = fminf(d, __shfl_xor(d, st));
    thr = d - 40.f;
  }

#define MFMA32(A, B, C) __builtin_amdgcn_mfma_f32_32x32x16_bf16(A, B, C, 0, 0, 0)

  // B tile (t): colblk = part*32 + t*2 + cg -> 16 KB contiguous fragment run.
  const char* Bbase = Xf + ((size_t)(part * 32 + cg) * 16384) + lane * 16;
  // group (t, g): 4 fragments at Bbase + t*32768 + g*4096 + j*1024.
#define LOADQ(Q, T, G)                                                          \
  do {                                                                          \
    const char* _p = Bbase + (size_t)(T) * 32768 + (G) * 4096;                  \
    Q[0] = *(const bf16x8*)(_p);                                                \
    Q[1] = *(const bf16x8*)(_p + 1024);                                         \
    Q[2] = *(const bf16x8*)(_p + 2048);                                         \
    Q[3] = *(const bf16x8*)(_p + 3072);                                         \
  } while (0)

  // 8 MFMAs on group regs Q with ks base K (4 chains by j-parity).
#define MM4(Q, K)                                                               \
  do {                                                                          \
    c00 = MFMA32(afrag[0][(K) + 0], Q[0], c00);                                 \
    c10 = MFMA32(afrag[1][(K) + 0], Q[0], c10);                                 \
    c01 = MFMA32(afrag[0][(K) + 1], Q[1], c01);                                 \
    c11 = MFMA32(afrag[1][(K) + 1], Q[1], c11);                                 \
    c00 = MFMA32(afrag[0][(K) + 2], Q[2], c00);                                 \
    c10 = MFMA32(afrag[1][(K) + 2], Q[2], c10);                                 \
    c01 = MFMA32(afrag[0][(K) + 3], Q[3], c01);                                 \
    c11 = MFMA32(afrag[1][(K) + 3], Q[3], c11);                                 \
  } while (0)

  bf16x8 q0[4], q1[4];
  LOADQ(q0, 0, 0);

  for (int t = 0; t < 16; ++t) {
    f32x16 c00 = {}, c01 = {}, c10 = {}, c11 = {};
    LOADQ(q1, t, 1);
    MM4(q0, 0);
    LOADQ(q0, t, 2);
    MM4(q1, 4);
    LOADQ(q1, t, 3);
    MM4(q0, 8);
    if (t < 15) LOADQ(q0, t + 1, 0);
    MM4(q1, 12);

    // ---- fused epilogue for tile t (registers + LDS atomics; no barrier) --
    {
      const int aT = abase + (t >> 1);
      const bool is_pos = (slab[aT] == myLab);
      f32x16 c0 = c00 + c01;
      f32x16 c1 = c10 + c11;
      float vmax = fmaxf(c0[0], c1[0]);
#pragma unroll
      for (int r = 1; r < 16; ++r) vmax = fmaxf(vmax, fmaxf(c0[r], c1[r]));
      const bool anyhot = __any(vmax > thr);
      const int gcol = part * 1024 + t * 64 + cg * 32 + l31;
      if (__builtin_expect(is_pos, 0)) {
        if (!anyhot) {
#pragma unroll
          for (int ri = 0; ri < 2; ++ri) {
#pragma unroll
            for (int r = 0; r < 16; ++r) {
              const int rloc = (r & 3) + 8 * (r >> 2) + 4 * khalf;
              const int row = rg * 64 + ri * 32 + rloc;
              float d = (ri ? c1[r] : c0[r]) - sdiag[row];
#pragma unroll
              for (int st = 1; st < 32; st <<= 1) d += __shfl_xor(d, st);
              if (l31 == 0) atomicAdd(&sdacc[row], d);
            }
          }
        } else {
#pragma unroll
          for (int ri = 0; ri < 2; ++ri) {
#pragma unroll
            for (int r = 0; r < 16; ++r) {
              const int rloc = (r & 3) + 8 * (r >> 2) + 4 * khalf;
              const int row = rg * 64 + ri * 32 + rloc;
              const bool isdiag = (R0 + row) == gcol;
              float v = (ri ? c1[r] : c0[r]);
              float d = v - sdiag[row];
              float sd_e = isdiag ? 0.f : d;
              float e = (!isdiag && d > -40.f) ? __expf(d) : 0.f;
#pragma unroll
              for (int st = 1; st < 32; st <<= 1) {
                sd_e += __shfl_xor(sd_e, st);
                e += __shfl_xor(e, st);
              }
              if (l31 == 0) {
                atomicAdd(&sdacc[row], sd_e);
                if (e != 0.f) atomicAdd(&epacc[row], e);
              }
            }
          }
        }
      } else if (__builtin_expect(anyhot, 0)) {
#pragma unroll
        for (int ri = 0; ri < 2; ++ri) {
#pragma unroll
          for (int r = 0; r < 16; ++r) {
            const int rloc = (r & 3) + 8 * (r >> 2) + 4 * khalf;
            const int row = rg * 64 + ri * 32 + rloc;
            float d = (ri ? c1[r] : c0[r]) - sdiag[row];
            float e = (d > -40.f) ? __expf(d) : 0.f;
#pragma unroll
            for (int st = 1; st < 32; st <<= 1) e += __shfl_xor(e, st);
            if (l31 == 0) atomicAdd(&nsacc[row], e);
          }
        }
      }
    }
  }

#undef MM4
#undef LOADQ
#undef MFMA32

  __syncthreads();
  if (tid < 256) {
    ns_partial[part * N_ROWS + R0 + tid] = nsacc[tid];
    sd_partial[part * N_ROWS + R0 + tid] = sdacc[tid];
    ep_partial[part * N_ROWS + R0 + tid] = epacc[tid];
  }
}

// -------- Kernel 3: per-row combine. 32 blocks x 256 threads, 1 row/thread.
// mean_log_prob_pos = (SD - npos*log(NS+eps) - EP/(NS+eps)) / npos
__global__ void pcl_combine(const int* __restrict__ labels,
                            const float* __restrict__ ns_partial,
                            const float* __restrict__ sd_partial,
                            const float* __restrict__ ep_partial,
                            float* __restrict__ partials) {
  const int tid = threadIdx.x;
  const int row = blockIdx.x * 256 + tid;
  __shared__ int slab[NANCH];
  __shared__ float sred[256];
  if (tid < NANCH) slab[tid] = labels[tid];
  __syncthreads();

  const int lab = slab[row >> 7];
  int cnt = 0;
#pragma unroll
  for (int b = 0; b < NANCH; ++b) cnt += (slab[b] == lab) ? 1 : 0;

  float NS = 0.f, SD = 0.f, EP = 0.f;
#pragma unroll
  for (int p = 0; p < NPART; ++p) {
    NS += ns_partial[p * N_ROWS + row];
    SD += sd_partial[p * N_ROWS + row];
    EP += ep_partial[p * N_ROWS + row];
  }
  const float npos = (float)(cnt * NVIEW - 1);
  const float nse = NS + 1e-10f;
  const float mlpp = (SD - npos * __logf(nse) - EP / nse) / npos;
  sred[tid] = mlpp;
  __syncthreads();
  for (int st = 128; st > 0; st >>= 1) {
    if (tid < st) sred[tid] += sred[tid + st];
    __syncthreads();
  }
  if (tid == 0) partials[blockIdx.x] = sred[0];
}

__global__ void final_reduce(const float* __restrict__ partials, float* __restrict__ out) {
  __shared__ float s[32];
  int t = threadIdx.x;
  if (t < 32) s[t] = partials[t];
  __syncthreads();
  if (t == 0) {
    float sum = 0.f;
    for (int r = 0; r < 32; ++r) sum += s[r];
    out[0] = -(0.1f / 0.07f) * sum / (float)N_ROWS;
  }
}

extern "C" void kernel_launch(void* const* d_in, const int* in_sizes, int n_in,
                              void* d_out, int out_size, void* d_ws, size_t ws_size,
                              hipStream_t stream) {
  const float* feats = (const float*)d_in[0];
  const int* labels = (const int*)d_in[1];
  float* out = (float*)d_out;

  char* base = (char*)d_ws;
  char* Xf = (char*)d_ws;                                          // 4 MB
  size_t off = (size_t)N_ROWS * DIM * 2;
  float* diag = (float*)(base + off);       off += N_ROWS * 4;     // 32 KB
  float* ns_partial = (float*)(base + off); off += (size_t)NPART * N_ROWS * 4;
  float* sd_partial = (float*)(base + off); off += (size_t)NPART * N_ROWS * 4;
  float* ep_partial = (float*)(base + off); off += (size_t)NPART * N_ROWS * 4;
  float* partials = (float*)(base + off);

  cast_diag_kernel<<<N_ROWS / 4, 256, 0, stream>>>((const float4v*)feats,
                                                   Xf, diag);
  pcl_negsum<<<32 * NPART, 512, 0, stream>>>(Xf, labels, diag, ns_partial,
                                             sd_partial, ep_partial);
  pcl_combine<<<N_ROWS / 256, 256, 0, stream>>>(labels, ns_partial, sd_partial,
                                                ep_partial, partials);
  final_reduce<<<1, 64, 0, stream>>>(partials, out);
}